// Round 1
// baseline (107.437 us; speedup 1.0000x reference)
//
#include <hip/hip_runtime.h>
#include <math.h>

#define DEV __device__ __forceinline__

DEV float fast_rcp(float x) { return __builtin_amdgcn_rcpf(x); }

// se3 exponential: inputs tau[3], phi[3]; outputs R (row-major 3x3), t[3].
// Uses K^2 = phi phi^T - |phi|^2 I (exact skew identity).
DEV void se3_exp(const float tau0, const float tau1, const float tau2,
                 const float x, const float y, const float z,
                 float R[9], float t[3]) {
    float th2 = x*x + y*y + z*z;
    float th  = sqrtf(th2);
    bool small = th < 1e-4f;
    float ts  = small ? 1.0f : th;
    float s   = __sinf(ts);
    float c   = __cosf(ts);
    float inv = fast_rcp(ts);
    float A = small ? (1.0f - th2 * (1.0f/6.0f))   : s * inv;
    float B = small ? (0.5f - th2 * (1.0f/24.0f))  : (1.0f - c) * inv * inv;
    float C = small ? (1.0f/6.0f - th2*(1.0f/120.0f)) : (ts - s) * inv * inv * inv;

    float Bxy = B*x*y, Bxz = B*x*z, Byz = B*y*z;
    R[0] = 1.0f - B*(y*y + z*z);
    R[1] = Bxy - A*z;
    R[2] = Bxz + A*y;
    R[3] = Bxy + A*z;
    R[4] = 1.0f - B*(x*x + z*z);
    R[5] = Byz - A*x;
    R[6] = Bxz - A*y;
    R[7] = Byz + A*x;
    R[8] = 1.0f - B*(x*x + y*y);

    float Cxy = C*x*y, Cxz = C*x*z, Cyz = C*y*z;
    float V0 = 1.0f - C*(y*y + z*z);
    float V1 = Cxy - B*z;
    float V2 = Cxz + B*y;
    float V3 = Cxy + B*z;
    float V4 = 1.0f - C*(x*x + z*z);
    float V5 = Cyz - B*x;
    float V6 = Cxz - B*y;
    float V7 = Cyz + B*x;
    float V8 = 1.0f - C*(x*x + y*y);
    t[0] = V0*tau0 + V1*tau1 + V2*tau2;
    t[1] = V3*tau0 + V4*tau1 + V5*tau2;
    t[2] = V6*tau0 + V7*tau1 + V8*tau2;
}

DEV void mat_mul(const float A[9], const float B[9], float C[9]) {
    #pragma unroll
    for (int i = 0; i < 3; i++)
        #pragma unroll
        for (int j = 0; j < 3; j++)
            C[i*3+j] = A[i*3+0]*B[0*3+j] + A[i*3+1]*B[1*3+j] + A[i*3+2]*B[2*3+j];
}

// C = A * B^T
DEV void mat_mul_bt(const float A[9], const float B[9], float C[9]) {
    #pragma unroll
    for (int i = 0; i < 3; i++)
        #pragma unroll
        for (int j = 0; j < 3; j++)
            C[i*3+j] = A[i*3+0]*B[j*3+0] + A[i*3+1]*B[j*3+1] + A[i*3+2]*B[j*3+2];
}

DEV void mat_vec(const float A[9], const float v[3], float o[3]) {
    #pragma unroll
    for (int i = 0; i < 3; i++)
        o[i] = A[i*3+0]*v[0] + A[i*3+1]*v[1] + A[i*3+2]*v[2];
}

// One block per trajectory. 128 threads; thread t handles pair (t, t+1), t<127.
// LDS rows padded to stride 13 (stride-12 reads would be 8-way bank conflicted).
__global__ __launch_bounds__(128)
void kin_kernel(const float* __restrict__ traj, const int* __restrict__ kidx,
                const float* __restrict__ tw, const float* __restrict__ kw,
                float* __restrict__ partial) {
    __shared__ float s[128 * 13];
    __shared__ float wsum[2];
    const int b   = blockIdx.x;
    const int tid = threadIdx.x;

    // Coalesced staging: 384 float4 per trajectory, 3 per thread; scatter into
    // padded LDS layout.
    const float4* g = (const float4*)(traj + (size_t)b * 1536);
    #pragma unroll
    for (int i = 0; i < 3; i++) {
        int f = tid + i * 128;
        float4 v = g[f];
        int e = f * 4;
        float vv[4] = {v.x, v.y, v.z, v.w};
        #pragma unroll
        for (int c = 0; c < 4; c++) {
            int ee  = e + c;
            int r   = ee / 12;          // const-div -> magic mul
            int col = ee - r * 12;
            s[r * 13 + col] = vv[c];
        }
    }
    __syncthreads();

    float term = 0.0f;
    if (tid < 127) {
        const float* a0 = &s[tid * 13];
        const float* a1 = &s[(tid + 1) * 13];

        float R1[9], t1[3], R2[9], t2[3];
        se3_exp(a0[0], a0[1], a0[2], a0[3], a0[4], a0[5], R1, t1);
        se3_exp(a0[6]*0.05f, a0[7]*0.05f, a0[8]*0.05f,
                a0[9]*0.05f, a0[10]*0.05f, a0[11]*0.05f, R2, t2);
        float Rf[9], tf[3], tmp[3];
        mat_mul(R2, R1, Rf);
        mat_vec(R2, t1, tmp);
        tf[0] = tmp[0] + t2[0]; tf[1] = tmp[1] + t2[1]; tf[2] = tmp[2] + t2[2];

        float R3[9], t3[3], R4[9], t4[3];
        se3_exp(a1[0], a1[1], a1[2], a1[3], a1[4], a1[5], R3, t3);
        se3_exp(a1[6]*-0.05f, a1[7]*-0.05f, a1[8]*-0.05f,
                a1[9]*-0.05f, a1[10]*-0.05f, a1[11]*-0.05f, R4, t4);
        float Rb[9], tb[3];
        mat_mul(R4, R3, Rb);
        mat_vec(R4, t3, tmp);
        tb[0] = tmp[0] + t4[0]; tb[1] = tmp[1] + t4[1]; tb[2] = tmp[2] + t4[2];

        // delta = fwd * inv(bwd):  Rd = Rf Rb^T ; td = tf - Rd tb
        float Rd[9], td[3];
        mat_mul_bt(Rf, Rb, Rd);
        mat_vec(Rd, tb, tmp);
        td[0] = tf[0] - tmp[0]; td[1] = tf[1] - tmp[1]; td[2] = tf[2] - tmp[2];

        // so3_log
        float tr = Rd[0] + Rd[4] + Rd[8];
        float cc = fminf(fmaxf((tr - 1.0f) * 0.5f, -1.0f + 1e-7f), 1.0f - 1e-7f);
        float th = acosf(cc);
        bool small = th < 1e-4f;
        float tsl = small ? 1.0f : th;
        float sn  = __sinf(tsl);
        float cs  = __cosf(tsl);
        float coef = small ? (0.5f + th*th*(1.0f/12.0f))
                           : tsl * fast_rcp(2.0f * sn);
        float px = coef * (Rd[7] - Rd[5]);
        float py = coef * (Rd[2] - Rd[6]);
        float pz = coef * (Rd[3] - Rd[1]);

        // se3_log: Vinv = I - 0.5 K + D (pp^T - |p|^2 I)
        float th2 = th * th;
        float D = small ? (1.0f/12.0f + th2*(1.0f/720.0f))
                        : (1.0f - tsl*sn*fast_rcp(2.0f*(1.0f - cs))) * fast_rcp(tsl*tsl);
        float Dxy = D*px*py, Dxz = D*px*pz, Dyz = D*py*pz;
        float Vi0 = 1.0f - D*(py*py + pz*pz);
        float Vi1 = Dxy + 0.5f*pz;
        float Vi2 = Dxz - 0.5f*py;
        float Vi3 = Dxy - 0.5f*pz;
        float Vi4 = 1.0f - D*(px*px + pz*pz);
        float Vi5 = Dyz + 0.5f*px;
        float Vi6 = Dxz + 0.5f*py;
        float Vi7 = Dyz - 0.5f*px;
        float Vi8 = 1.0f - D*(px*px + py*py);
        float ux = Vi0*td[0] + Vi1*td[1] + Vi2*td[2];
        float uy = Vi3*td[0] + Vi4*td[1] + Vi5*td[2];
        float uz = Vi6*td[0] + Vi7*td[1] + Vi8*td[2];

        float loss = ux*ux + uy*uy + uz*uz + px*px + py*py + pz*pz;
        term = loss * tw[tid];
    }

    // block reduction: 2 waves
    float v = term;
    #pragma unroll
    for (int off = 32; off; off >>= 1) v += __shfl_down(v, off, 64);
    if ((tid & 63) == 0) wsum[tid >> 6] = v;
    __syncthreads();
    if (tid == 0) {
        partial[b] = (wsum[0] + wsum[1]) * kw[kidx[b]];
    }
}

__global__ __launch_bounds__(256)
void reduce_kernel(const float* __restrict__ partial, float* __restrict__ out, int n) {
    __shared__ float ws[4];
    int tid = threadIdx.x;
    float v = 0.0f;
    for (int i = tid; i < n; i += 256) v += partial[i];
    #pragma unroll
    for (int off = 32; off; off >>= 1) v += __shfl_down(v, off, 64);
    if ((tid & 63) == 0) ws[tid >> 6] = v;
    __syncthreads();
    if (tid == 0) {
        float total = ws[0] + ws[1] + ws[2] + ws[3];
        out[0] = total * (1.0f / (127.0f * 8192.0f));
    }
}

extern "C" void kernel_launch(void* const* d_in, const int* in_sizes, int n_in,
                              void* d_out, int out_size, void* d_ws, size_t ws_size,
                              hipStream_t stream) {
    const float* traj = (const float*)d_in[0];
    const int*   k    = (const int*)d_in[1];
    const float* tw   = (const float*)d_in[2];
    const float* kw   = (const float*)d_in[3];
    float* out     = (float*)d_out;
    float* partial = (float*)d_ws;
    const int B = in_sizes[1];  // 8192 trajectories

    kin_kernel<<<B, 128, 0, stream>>>(traj, k, tw, kw, partial);
    reduce_kernel<<<1, 256, 0, stream>>>(partial, out, B);
}